// Round 3
// baseline (234.798 us; speedup 1.0000x reference)
//
#include <hip/hip_runtime.h>
#include <hip/hip_bf16.h>

typedef __attribute__((ext_vector_type(8))) short short8;
typedef __attribute__((ext_vector_type(4))) float floatx4;
typedef __attribute__((ext_vector_type(4))) float float4v;
typedef __attribute__((ext_vector_type(4))) unsigned short ushort4v;

#define TILE_M 64
#define LDS_STRIDE 264  // 256 shorts + 8 pad -> 528B row stride

static __device__ __forceinline__ unsigned short f2bf(float x) {
    // round-to-nearest-even fp32 -> bf16 (inputs are finite normals)
    unsigned int u = __builtin_bit_cast(unsigned int, x);
    unsigned int r = (u + 0x7FFFu + ((u >> 16) & 1u)) >> 16;
    return (unsigned short)r;
}

// One prep launch: convert both tables fp32->bf16 (float4-vectorized) AND
// transpose W1 [256k][128n] -> w1t [128n][256k] bf16.
__global__ void prep_all(const float* __restrict__ zd, const float* __restrict__ zs,
                         const float* __restrict__ W1,
                         int nd4, int ns4,
                         unsigned short* __restrict__ outd, unsigned short* __restrict__ outs,
                         unsigned short* __restrict__ w1t) {
    int i = blockIdx.x * 256 + threadIdx.x;
    int total4 = nd4 + ns4;
    if (i < total4) {
        const float* src; unsigned short* dst; int j;
        if (i < nd4) { src = zd; dst = outd; j = i; }
        else         { src = zs; dst = outs; j = i - nd4; }
        float4v v = *reinterpret_cast<const float4v*>(src + (size_t)j * 4);
        ushort4v o;
        o.x = f2bf(v.x); o.y = f2bf(v.y); o.z = f2bf(v.z); o.w = f2bf(v.w);
        *reinterpret_cast<ushort4v*>(dst + (size_t)j * 4) = o;
    } else {
        int j = i - total4;           // 0..32767
        if (j < 128 * 256) {
            int n = j >> 8;
            int k = j & 255;
            w1t[n * 256 + k] = f2bf(W1[k * 128 + n]);
        }
    }
}

__global__ __launch_bounds__(256, 4) void edge_mlp(
    const unsigned short* __restrict__ zd, const unsigned short* __restrict__ zs,
    const int* __restrict__ row, const int* __restrict__ col,
    const unsigned short* __restrict__ w1t,
    const float* __restrict__ b1, const float* __restrict__ w2,
    const float* __restrict__ b2, float* __restrict__ out, int ntiles)
{
    __shared__ unsigned short lds_a[TILE_M * LDS_STRIDE];   // 33 KiB
    __shared__ float red[4][TILE_M];                        // 1 KiB

    const int tid = threadIdx.x;
    const int lane = tid & 63;
    const int wave = tid >> 6;      // wave owns hidden units [wave*32, wave*32+32)
    const int l15 = lane & 15;
    const int quad = lane >> 4;
    const int wbase = wave * 32;

    // ---- persistent: all W1 A-fragments for this wave's hidden range (64 VGPRs) ----
    // A[m=hidden][k]: m = lane&15, k = quad*8+j  ->  w1t[(wbase+mt*16+l15)*256 + s*32 + quad*8]
    short8 wfrag[16];               // [s*2 + mt]
    #pragma unroll
    for (int s = 0; s < 8; ++s)
        #pragma unroll
        for (int mt = 0; mt < 2; ++mt)
            wfrag[s * 2 + mt] = *reinterpret_cast<const short8*>(
                &w1t[(size_t)(wbase + mt * 16 + l15) * 256 + s * 32 + quad * 8]);

    const float b2v = b2[0];

    for (int t = blockIdx.x; t < ntiles; t += gridDim.x) {
        const long ebase = (long)t * TILE_M;

        // ---- stage A tile: 64 edges x 256 bf16 (drug ++ disease), 16B/thread/iter ----
        #pragma unroll
        for (int i = 0; i < 8; ++i) {
            int c = tid + 256 * i;          // 32 x 16B chunks per edge
            int e = c >> 5;
            int cc = c & 31;                // 0..15 drug half, 16..31 disease half
            int isdis = cc >> 4;
            int idx = isdis ? col[ebase + e] : row[ebase + e];
            const unsigned short* src = (isdis ? zs : zd) + (size_t)idx * 128 + (size_t)(cc & 15) * 8;
            short8 v = *reinterpret_cast<const short8*>(src);
            *reinterpret_cast<short8*>(&lds_a[e * LDS_STRIDE + cc * 8]) = v;
        }

        __syncthreads();

        // ---- K loop: C[hidden, edge] = W1^T-tile x edge-tile ----
        floatx4 acc[4][2];              // [et][mt]
        #pragma unroll
        for (int et = 0; et < 4; ++et)
            #pragma unroll
            for (int mt = 0; mt < 2; ++mt)
                acc[et][mt] = (floatx4)(0.0f);

        #pragma unroll
        for (int s = 0; s < 8; ++s) {
            short8 ef[4];
            #pragma unroll
            for (int et = 0; et < 4; ++et) {
                int e = et * 16 + l15;      // B[k][n=edge]: n = lane&15, k = quad*8+j
                ef[et] = *reinterpret_cast<const short8*>(&lds_a[e * LDS_STRIDE + s * 32 + quad * 8]);
            }
            #pragma unroll
            for (int et = 0; et < 4; ++et)
                #pragma unroll
                for (int mt = 0; mt < 2; ++mt)
                    acc[et][mt] = __builtin_amdgcn_mfma_f32_16x16x32_bf16(
                        wfrag[s * 2 + mt], ef[et], acc[et][mt], 0, 0, 0);
        }

        // ---- epilogue: out[e] = sum_h relu(C[h][e]+b1[h]) * w2[h] + b2 ----
        // C layout: edge = lane&15, hidden = quad*4 + reg (+ mt*16 + wbase)
        float4v b1v[2], w2v[2];
        #pragma unroll
        for (int mt = 0; mt < 2; ++mt) {
            b1v[mt] = *reinterpret_cast<const float4v*>(&b1[wbase + mt * 16 + quad * 4]);
            w2v[mt] = *reinterpret_cast<const float4v*>(&w2[wbase + mt * 16 + quad * 4]);
        }
        #pragma unroll
        for (int et = 0; et < 4; ++et) {
            float v = 0.f;
            #pragma unroll
            for (int mt = 0; mt < 2; ++mt) {
                #pragma unroll
                for (int r = 0; r < 4; ++r) {
                    float h = acc[et][mt][r] + b1v[mt][r];
                    h = h > 0.f ? h : 0.f;
                    v += h * w2v[mt][r];
                }
            }
            // reduce across the 4 quads (hidden within this wave's 32)
            v += __shfl_xor(v, 16);
            v += __shfl_xor(v, 32);
            if (lane < 16)
                red[wave][et * 16 + l15] = v;
        }

        __syncthreads();
        if (tid < TILE_M)
            out[ebase + tid] = red[0][tid] + red[1][tid] + red[2][tid] + red[3][tid] + b2v;
    }
}

extern "C" void kernel_launch(void* const* d_in, const int* in_sizes, int n_in,
                              void* d_out, int out_size, void* d_ws, size_t ws_size,
                              hipStream_t stream) {
    const float* zd = (const float*)d_in[0];
    const float* zs = (const float*)d_in[1];
    const int*   row = (const int*)d_in[2];
    const int*   col = (const int*)d_in[3];
    const float* W1 = (const float*)d_in[4];
    const float* b1 = (const float*)d_in[5];
    const float* w2 = (const float*)d_in[6];
    const float* b2 = (const float*)d_in[7];
    float* out = (float*)d_out;

    const int nd = in_sizes[0];   // 10000*128
    const int ns = in_sizes[1];   // 15000*128
    const int E  = in_sizes[2];   // 1048576

    unsigned short* zd_b = (unsigned short*)d_ws;
    unsigned short* zs_b = zd_b + nd;
    unsigned short* w1t  = zs_b + ns;   // 128*256 bf16

    const int total_jobs = (nd + ns) / 4 + 128 * 256;
    const int pgrid = (total_jobs + 255) / 256;
    hipLaunchKernelGGL(prep_all, dim3(pgrid), dim3(256), 0, stream,
                       zd, zs, W1, nd / 4, ns / 4, zd_b, zs_b, w1t);

    const int ntiles = E / TILE_M;   // 16384
    const int nblocks = 1024;        // 4 blocks/CU x 256 CUs, persistent grid-stride
    hipLaunchKernelGGL(edge_mlp, dim3(nblocks), dim3(256), 0, stream,
                       zd_b, zs_b, row, col, w1t, b1, w2, b2, out, ntiles);
}

// Round 4
// 158.336 us; speedup vs baseline: 1.4829x; 1.4829x over previous
//
#include <hip/hip_runtime.h>

typedef __attribute__((ext_vector_type(8))) short short8;
typedef __attribute__((ext_vector_type(4))) float floatx4;
typedef __attribute__((ext_vector_type(4))) float float4v;
typedef __attribute__((ext_vector_type(4))) unsigned short ushort4v;

#define TILE_M 64
#define TILE_SHORTS (TILE_M * 256)   // 16384 shorts = 32 KB per buffer (flat, swizzled)

static __device__ __forceinline__ unsigned short f2bf(float x) {
    unsigned int u = __builtin_bit_cast(unsigned int, x);
    unsigned int r = (u + 0x7FFFu + ((u >> 16) & 1u)) >> 16;
    return (unsigned short)r;
}

// async 16B global -> LDS (DMA, lands at lds_base + lane*16)
static __device__ __forceinline__ void gld16(const unsigned short* g, unsigned short* l) {
    __builtin_amdgcn_global_load_lds(
        (const __attribute__((address_space(1))) unsigned int*)g,
        (__attribute__((address_space(3))) unsigned int*)l, 16, 0, 0);
}

// One prep launch: tables fp32->bf16 (vectorized) + W1 [256k][128n] -> w1t [128n][256k] bf16
__global__ void prep_all(const float* __restrict__ zd, const float* __restrict__ zs,
                         const float* __restrict__ W1,
                         int nd4, int ns4,
                         unsigned short* __restrict__ outd, unsigned short* __restrict__ outs,
                         unsigned short* __restrict__ w1t) {
    int i = blockIdx.x * 256 + threadIdx.x;
    int total4 = nd4 + ns4;
    if (i < total4) {
        const float* src; unsigned short* dst; int j;
        if (i < nd4) { src = zd; dst = outd; j = i; }
        else         { src = zs; dst = outs; j = i - nd4; }
        float4v v = *reinterpret_cast<const float4v*>(src + (size_t)j * 4);
        ushort4v o;
        o.x = f2bf(v.x); o.y = f2bf(v.y); o.z = f2bf(v.z); o.w = f2bf(v.w);
        *reinterpret_cast<ushort4v*>(dst + (size_t)j * 4) = o;
    } else {
        int j = i - total4;
        if (j < 128 * 256) {
            int n = j >> 8;
            int k = j & 255;
            w1t[n * 256 + k] = f2bf(W1[k * 128 + n]);
        }
    }
}

// Layout of an edge tile in LDS (flat, DMA-compatible, XOR-swizzled):
// chunk slot c (c = 0..2047, 16B each) holds edge e = c>>5, physical chunk jx = c&31,
// which stores LOGICAL k-chunk j = jx ^ (e&7) of edge e's 256-short concat row
// (j<16: drug half, j>=16: disease half). Readers invert the same XOR.
__global__ __launch_bounds__(256, 2) void edge_mlp(
    const unsigned short* __restrict__ zd, const unsigned short* __restrict__ zs,
    const int* __restrict__ row, const int* __restrict__ col,
    const unsigned short* __restrict__ w1t,
    const float* __restrict__ b1, const float* __restrict__ w2,
    const float* __restrict__ b2, float* __restrict__ out, int ntiles)
{
    __shared__ unsigned short lds_a[2][TILE_SHORTS];  // 64 KB double buffer
    __shared__ float red[2][4][TILE_M];               // 2 KB, parity-buffered

    const int tid  = threadIdx.x;
    const int lane = tid & 63;
    const int wave = tid >> 6;           // wave owns hidden [wave*32, wave*32+32)
    const int l15  = lane & 15;
    const int quad = lane >> 4;
    const int wbase = wave * 32;

    // ---- persistent W1 A-fragments (64 VGPRs) ----
    short8 wfrag[16];                    // [s*2 + mt]
    #pragma unroll
    for (int s = 0; s < 8; ++s)
        #pragma unroll
        for (int mt = 0; mt < 2; ++mt)
            wfrag[s * 2 + mt] = *reinterpret_cast<const short8*>(
                &w1t[(size_t)(wbase + mt * 16 + l15) * 256 + s * 32 + quad * 8]);

    // ---- persistent epilogue constants ----
    float4v b1v[2], w2v[2];
    #pragma unroll
    for (int mt = 0; mt < 2; ++mt) {
        b1v[mt] = *reinterpret_cast<const float4v*>(&b1[wbase + mt * 16 + quad * 4]);
        w2v[mt] = *reinterpret_cast<const float4v*>(&w2[wbase + mt * 16 + quad * 4]);
    }
    const float b2v = b2[0];

    // ---- fixed staging geometry for this thread ----
    const int e0 = tid >> 5;             // edge low bits: edges e0 + 8i
    const int jxw = tid & 31;            // physical chunk this thread fills
    const int jlog = jxw ^ (e0 & 7);     // logical k-chunk it must fetch
    const unsigned short* tab = (jlog >= 16) ? zs : zd;
    const int* idxp = (jlog >= 16) ? col : row;
    const int koff = (jlog & 15) * 8;    // shorts within the 128-short row

    // reader swizzle constants
    const int hb = (l15 >> 2) & 1;       // XOR bit folded into s
    const int qx = quad ^ (l15 & 3);     // XOR folded into quad

    const int G = gridDim.x;
    long t0 = blockIdx.x;

    // ---- prologue: fill buffer 0 for tile t0; prefetch indices for t0+G ----
    int nidx[8];
    #pragma unroll
    for (int i = 0; i < 8; ++i) nidx[i] = idxp[t0 * TILE_M + e0 + 8 * i];
    #pragma unroll
    for (int i = 0; i < 8; ++i)
        gld16(tab + (size_t)nidx[i] * 128 + koff, &lds_a[0][2048 * i + 512 * wave]);
    {
        long t1 = t0 + G; if (t1 >= ntiles) t1 = t0;
        #pragma unroll
        for (int i = 0; i < 8; ++i) nidx[i] = idxp[t1 * TILE_M + e0 + 8 * i];
    }
    __syncthreads();   // drains the DMA (vmcnt(0)) before first K-loop

    int parity = 0;
    for (long tc = t0; tc < ntiles; tc += G, parity ^= 1) {
        // (a) issue async gather for tile tc+G into the other buffer (covers the whole K-loop)
        long tn = tc + G;
        if (tn < ntiles) {
            #pragma unroll
            for (int i = 0; i < 8; ++i)
                gld16(tab + (size_t)nidx[i] * 128 + koff,
                      &lds_a[parity ^ 1][2048 * i + 512 * wave]);
        }
        // (b) prefetch indices for tile tc+2G
        {
            long t2 = tc + 2 * (long)G; if (t2 >= ntiles) t2 = tc;
            #pragma unroll
            for (int i = 0; i < 8; ++i) nidx[i] = idxp[t2 * TILE_M + e0 + 8 * i];
        }

        // (c) K-loop on buffer[parity]: C[hidden, edge] += W1^T x Z
        const unsigned short* buf = lds_a[parity];
        floatx4 acc[4][2];
        #pragma unroll
        for (int et = 0; et < 4; ++et)
            #pragma unroll
            for (int mt = 0; mt < 2; ++mt)
                acc[et][mt] = (floatx4)(0.0f);

        #pragma unroll
        for (int s = 0; s < 8; ++s) {
            const int sx = s ^ hb;
            short8 ef[4];
            #pragma unroll
            for (int et = 0; et < 4; ++et) {
                int e = et * 16 + l15;
                ef[et] = *reinterpret_cast<const short8*>(&buf[e * 256 + sx * 32 + qx * 8]);
            }
            #pragma unroll
            for (int et = 0; et < 4; ++et)
                #pragma unroll
                for (int mt = 0; mt < 2; ++mt)
                    acc[et][mt] = __builtin_amdgcn_mfma_f32_16x16x32_bf16(
                        wfrag[s * 2 + mt], ef[et], acc[et][mt], 0, 0, 0);
        }

        // (d) epilogue: partial out[e] per wave -> red[parity]
        // C layout: edge = lane&15, hidden = wbase + mt*16 + quad*4 + r
        #pragma unroll
        for (int et = 0; et < 4; ++et) {
            float v = 0.f;
            #pragma unroll
            for (int mt = 0; mt < 2; ++mt)
                #pragma unroll
                for (int r = 0; r < 4; ++r) {
                    float h = acc[et][mt][r] + b1v[mt][r];
                    h = h > 0.f ? h : 0.f;
                    v += h * w2v[mt][r];
                }
            v += __shfl_xor(v, 16);
            v += __shfl_xor(v, 32);
            if (lane < 16) red[parity][wave][et * 16 + l15] = v;
        }

        // one barrier per tile: orders red write->read, cur-buffer reads vs next DMA
        // writes, and drains this iteration's DMA (vmcnt(0)) for the next K-loop.
        __syncthreads();

        if (tid < TILE_M)
            out[tc * TILE_M + tid] = red[parity][0][tid] + red[parity][1][tid]
                                   + red[parity][2][tid] + red[parity][3][tid] + b2v;
    }
}

extern "C" void kernel_launch(void* const* d_in, const int* in_sizes, int n_in,
                              void* d_out, int out_size, void* d_ws, size_t ws_size,
                              hipStream_t stream) {
    const float* zd = (const float*)d_in[0];
    const float* zs = (const float*)d_in[1];
    const int*   row = (const int*)d_in[2];
    const int*   col = (const int*)d_in[3];
    const float* W1 = (const float*)d_in[4];
    const float* b1 = (const float*)d_in[5];
    const float* w2 = (const float*)d_in[6];
    const float* b2 = (const float*)d_in[7];
    float* out = (float*)d_out;

    const int nd = in_sizes[0];   // 10000*128
    const int ns = in_sizes[1];   // 15000*128
    const int E  = in_sizes[2];   // 1048576

    unsigned short* zd_b = (unsigned short*)d_ws;
    unsigned short* zs_b = zd_b + nd;
    unsigned short* w1t  = zs_b + ns;   // 128*256 bf16

    const int total_jobs = (nd + ns) / 4 + 128 * 256;
    const int pgrid = (total_jobs + 255) / 256;
    hipLaunchKernelGGL(prep_all, dim3(pgrid), dim3(256), 0, stream,
                       zd, zs, W1, nd / 4, ns / 4, zd_b, zs_b, w1t);

    const int ntiles = E / TILE_M;   // 16384
    const int nblocks = 512;         // 2 blocks/CU (LDS-limited), persistent grid-stride
    hipLaunchKernelGGL(edge_mlp, dim3(nblocks), dim3(256), 0, stream,
                       zd_b, zs_b, row, col, w1t, b1, w2, b2, out, ntiles);
}

// Round 5
// 154.643 us; speedup vs baseline: 1.5183x; 1.0239x over previous
//
#include <hip/hip_runtime.h>

typedef __attribute__((ext_vector_type(8))) short short8;
typedef __attribute__((ext_vector_type(4))) float floatx4;
typedef __attribute__((ext_vector_type(4))) float float4v;
typedef __attribute__((ext_vector_type(4))) unsigned short ushort4v;

#define TILE_M 64
#define TILE_SHORTS (TILE_M * 256)   // 16384 shorts = 32 KB per buffer (flat, swizzled)

static __device__ __forceinline__ unsigned short f2bf(float x) {
    unsigned int u = __builtin_bit_cast(unsigned int, x);
    unsigned int r = (u + 0x7FFFu + ((u >> 16) & 1u)) >> 16;
    return (unsigned short)r;
}

// async 16B global -> LDS (DMA, lands at lds_base + lane*16)
static __device__ __forceinline__ void gld16(const unsigned short* g, unsigned short* l) {
    __builtin_amdgcn_global_load_lds(
        (const __attribute__((address_space(1))) unsigned int*)g,
        (__attribute__((address_space(3))) unsigned int*)l, 16, 0, 0);
}

// One prep launch: tables fp32->bf16 (vectorized) + W1 [256k][128n] -> w1t [128n][256k] bf16
__global__ void prep_all(const float* __restrict__ zd, const float* __restrict__ zs,
                         const float* __restrict__ W1,
                         int nd4, int ns4,
                         unsigned short* __restrict__ outd, unsigned short* __restrict__ outs,
                         unsigned short* __restrict__ w1t) {
    int i = blockIdx.x * 256 + threadIdx.x;
    int total4 = nd4 + ns4;
    if (i < total4) {
        const float* src; unsigned short* dst; int j;
        if (i < nd4) { src = zd; dst = outd; j = i; }
        else         { src = zs; dst = outs; j = i - nd4; }
        float4v v = *reinterpret_cast<const float4v*>(src + (size_t)j * 4);
        ushort4v o;
        o.x = f2bf(v.x); o.y = f2bf(v.y); o.z = f2bf(v.z); o.w = f2bf(v.w);
        *reinterpret_cast<ushort4v*>(dst + (size_t)j * 4) = o;
    } else {
        int j = i - total4;
        if (j < 128 * 256) {
            int n = j >> 8;
            int k = j & 255;
            w1t[n * 256 + k] = f2bf(W1[k * 128 + n]);
        }
    }
}

// LDS tile layout (flat, DMA-compatible, XOR-swizzled):
// chunk slot c (16B) holds edge e = c>>5, physical chunk jx = c&31, storing
// logical k-chunk j = jx ^ (e&7) of edge e's 256-short concat row.
__global__ __launch_bounds__(256, 2) void edge_mlp(
    const unsigned short* __restrict__ zd, const unsigned short* __restrict__ zs,
    const int* __restrict__ row, const int* __restrict__ col,
    const unsigned short* __restrict__ w1t,
    const float* __restrict__ b1, const float* __restrict__ w2,
    const float* __restrict__ b2, float* __restrict__ out, int ntiles)
{
    __shared__ unsigned short lds_a[2][TILE_SHORTS];  // 64 KB double buffer
    __shared__ float red[2][2][TILE_M];               // 1 KB, parity-buffered

    const int tid  = threadIdx.x;
    const int lane = tid & 63;
    const int wave = tid >> 6;
    const int wh   = wave >> 1;          // hidden half: [wh*64, wh*64+64)
    const int we   = wave & 1;           // edge half:   [we*32, we*32+32)
    const int l15  = lane & 15;
    const int quad = lane >> 4;
    const int whbase = wh * 64;

    // ---- persistent W1 A-fragments: this wave's 64 hidden x 256 k (128 VGPRs) ----
    // A[m=hidden][k]: m = lane&15, k = quad*8 + j
    short8 wfrag[32];                    // [s*4 + mt]
    #pragma unroll
    for (int s = 0; s < 8; ++s)
        #pragma unroll
        for (int mt = 0; mt < 4; ++mt)
            wfrag[s * 4 + mt] = *reinterpret_cast<const short8*>(
                &w1t[(size_t)(whbase + mt * 16 + l15) * 256 + s * 32 + quad * 8]);

    const float b2v = b2[0];

    // ---- fixed staging geometry for this thread ----
    const int e0 = tid >> 5;             // edges e0 + 8i
    const int jxw = tid & 31;            // physical chunk this thread fills
    const int jlog = jxw ^ (e0 & 7);     // logical k-chunk it fetches
    const unsigned short* tab = (jlog >= 16) ? zs : zd;
    const int* idxp = (jlog >= 16) ? col : row;
    const int koff = (jlog & 15) * 8;

    // reader swizzle constants
    const int hb = (l15 >> 2) & 1;
    const int qx = quad ^ (l15 & 3);

    const int G = gridDim.x;
    long t0 = blockIdx.x;

    // ---- prologue: fill buffer 0 for t0; prefetch indices for t0+G ----
    int nidx[8];
    #pragma unroll
    for (int i = 0; i < 8; ++i) nidx[i] = idxp[t0 * TILE_M + e0 + 8 * i];
    #pragma unroll
    for (int i = 0; i < 8; ++i)
        gld16(tab + (size_t)nidx[i] * 128 + koff, &lds_a[0][2048 * i + 512 * wave]);
    {
        long t1 = t0 + G; if (t1 >= ntiles) t1 = t0;
        #pragma unroll
        for (int i = 0; i < 8; ++i) nidx[i] = idxp[t1 * TILE_M + e0 + 8 * i];
    }
    __syncthreads();

    int parity = 0;
    for (long tc = t0; tc < ntiles; tc += G, parity ^= 1) {
        // (a) async gather for tile tc+G into the other buffer
        long tn = tc + G;
        if (tn < ntiles) {
            #pragma unroll
            for (int i = 0; i < 8; ++i)
                gld16(tab + (size_t)nidx[i] * 128 + koff,
                      &lds_a[parity ^ 1][2048 * i + 512 * wave]);
        }
        // (b) prefetch indices for tile tc+2G
        {
            long t2 = tc + 2 * (long)G; if (t2 >= ntiles) t2 = tc;
            #pragma unroll
            for (int i = 0; i < 8; ++i) nidx[i] = idxp[t2 * TILE_M + e0 + 8 * i];
        }

        // (c) K-loop: C[hidden64, edge32] += W1half^T x Zhalf
        const unsigned short* buf = lds_a[parity];
        floatx4 acc[2][4];               // [et][mt]
        #pragma unroll
        for (int et = 0; et < 2; ++et)
            #pragma unroll
            for (int mt = 0; mt < 4; ++mt)
                acc[et][mt] = (floatx4)(0.0f);

        #pragma unroll
        for (int s = 0; s < 8; ++s) {
            const int sx = s ^ hb;
            short8 ef[2];
            #pragma unroll
            for (int et = 0; et < 2; ++et) {
                int e = we * 32 + et * 16 + l15;
                ef[et] = *reinterpret_cast<const short8*>(&buf[e * 256 + sx * 32 + qx * 8]);
            }
            #pragma unroll
            for (int et = 0; et < 2; ++et)
                #pragma unroll
                for (int mt = 0; mt < 4; ++mt)
                    acc[et][mt] = __builtin_amdgcn_mfma_f32_16x16x32_bf16(
                        wfrag[s * 4 + mt], ef[et], acc[et][mt], 0, 0, 0);
        }

        // (d) epilogue: partial out over this wave's 64 hidden
        // C layout: edge = lane&15, hidden = whbase + mt*16 + quad*4 + r
        float4v b1v[4], w2v[4];
        #pragma unroll
        for (int mt = 0; mt < 4; ++mt) {
            b1v[mt] = *reinterpret_cast<const float4v*>(&b1[whbase + mt * 16 + quad * 4]);
            w2v[mt] = *reinterpret_cast<const float4v*>(&w2[whbase + mt * 16 + quad * 4]);
        }
        #pragma unroll
        for (int et = 0; et < 2; ++et) {
            float v = 0.f;
            #pragma unroll
            for (int mt = 0; mt < 4; ++mt)
                #pragma unroll
                for (int r = 0; r < 4; ++r) {
                    float h = acc[et][mt][r] + b1v[mt][r];
                    h = h > 0.f ? h : 0.f;
                    v += h * w2v[mt][r];
                }
            v += __shfl_xor(v, 16);
            v += __shfl_xor(v, 32);
            if (lane < 16) red[parity][wh][we * 32 + et * 16 + l15] = v;
        }

        // one barrier per tile: red ordering + buffer handoff + DMA drain
        __syncthreads();

        if (tid < TILE_M)
            out[tc * TILE_M + tid] = red[parity][0][tid] + red[parity][1][tid] + b2v;
    }
}

extern "C" void kernel_launch(void* const* d_in, const int* in_sizes, int n_in,
                              void* d_out, int out_size, void* d_ws, size_t ws_size,
                              hipStream_t stream) {
    const float* zd = (const float*)d_in[0];
    const float* zs = (const float*)d_in[1];
    const int*   row = (const int*)d_in[2];
    const int*   col = (const int*)d_in[3];
    const float* W1 = (const float*)d_in[4];
    const float* b1 = (const float*)d_in[5];
    const float* w2 = (const float*)d_in[6];
    const float* b2 = (const float*)d_in[7];
    float* out = (float*)d_out;

    const int nd = in_sizes[0];   // 10000*128
    const int ns = in_sizes[1];   // 15000*128
    const int E  = in_sizes[2];   // 1048576

    unsigned short* zd_b = (unsigned short*)d_ws;
    unsigned short* zs_b = zd_b + nd;
    unsigned short* w1t  = zs_b + ns;   // 128*256 bf16

    const int total_jobs = (nd + ns) / 4 + 128 * 256;
    const int pgrid = (total_jobs + 255) / 256;
    hipLaunchKernelGGL(prep_all, dim3(pgrid), dim3(256), 0, stream,
                       zd, zs, W1, nd / 4, ns / 4, zd_b, zs_b, w1t);

    const int ntiles = E / TILE_M;   // 16384
    const int nblocks = 512;         // 2 blocks/CU (LDS-limited), persistent grid-stride
    hipLaunchKernelGGL(edge_mlp, dim3(nblocks), dim3(256), 0, stream,
                       zd_b, zs_b, row, col, w1t, b1, w2, b2, out, ntiles);
}